// Round 1
// baseline (246.879 us; speedup 1.0000x reference)
//
#include <hip/hip_runtime.h>
#include <hip/hip_bf16.h>

// SE3 equivariant cross attention, MI355X gfx950.
// Design notes (round 1):
//  - edge-bias MLP (19 GFLOP naive) replaced by 2048-entry distance table per head
//    (bias is a smooth scalar function of d; nearest-lookup err ~0.007 << 0.6 thr).
//  - all matmuls via v_mfma_f32_32x32x16_bf16 (no fp32 MFMA on CDNA4).
//  - flash attention with NO running max: scores (log2 domain) provably < ~110,
//    exp2 never overflows; masked pairs -> p = 0 exactly.
//  - swapped QK^T (S^T = K·Q^T) so softmax/bias/coord work is lane-local;
//    P^T -> B-fragment via pack2 + shfl_xor(32) half-exchange.
//  - V projected directly into V^T layout [h*64+d][j] so PV A-frags are 16B loads.

#define NLIG   1024
#define NPOCK  8192
#define HIDDEN 256
#define ADIM   512
#define NHEAD  4
#define HDIM   64
#define NTAB   2048
#define NSPLIT 16
#define CHUNK  (NPOCK / NSPLIT)   // 512
#define LOG2E  1.4426950408889634f
#define QK_SCALE (0.125f * LOG2E) // 1/sqrt(64) * log2(e)

typedef float f32x16 __attribute__((ext_vector_type(16)));
typedef short short8 __attribute__((ext_vector_type(8)));

union U4S8 { uint4 u; short8 s; };

static __device__ __forceinline__ float exp2h(float x) {
  float r; asm("v_exp_f32 %0, %1" : "=v"(r) : "v"(x)); return r;
}
static __device__ __forceinline__ float rsqh(float x) {
  float r; asm("v_rsq_f32 %0, %1" : "=v"(r) : "v"(x)); return r;
}
static __device__ __forceinline__ unsigned short f2bf(float f) {
  union { __hip_bfloat16 h; unsigned short u; } c;
  c.h = __float2bfloat16(f);
  return c.u;
}
static __device__ __forceinline__ float bf2f(unsigned short u) {
  union { unsigned uu; float f; } c;
  c.uu = ((unsigned)u) << 16;
  return c.f;
}
static __device__ __forceinline__ unsigned pack2(float lo, float hi) {
  return (unsigned)f2bf(lo) | ((unsigned)f2bf(hi) << 16);
}
static __device__ __forceinline__ short8 load_bf8(const unsigned short* p) {
  U4S8 t; t.u = *(const uint4*)p; return t.s;
}
static __device__ __forceinline__ f32x16 mfma32(short8 a, short8 b, f32x16 c) {
  return __builtin_amdgcn_mfma_f32_32x32x16_bf16(a, b, c, 0, 0, 0);
}

// ---------------- k0a: fp32 -> bf16 casts (h_atomica, h_lig) ----------------
__global__ __launch_bounds__(256)
void cast_bf16_kernel(const float* __restrict__ hA, const float* __restrict__ hl,
                      unsigned short* __restrict__ hAb, unsigned short* __restrict__ hlb) {
  int id = blockIdx.x * 256 + threadIdx.x;
  const int nA4 = NPOCK * ADIM / 4;
  const int nL4 = NLIG * HIDDEN / 4;
  if (id < nA4) {
    float4 v = ((const float4*)hA)[id];
    ushort4 o; o.x = f2bf(v.x); o.y = f2bf(v.y); o.z = f2bf(v.z); o.w = f2bf(v.w);
    ((ushort4*)hAb)[id] = o;
  } else if (id < nA4 + nL4) {
    int j = id - nA4;
    float4 v = ((const float4*)hl)[j];
    ushort4 o; o.x = f2bf(v.x); o.y = f2bf(v.y); o.z = f2bf(v.z); o.w = f2bf(v.w);
    ((ushort4*)hlb)[j] = o;
  }
}

// ------------- k0b: weight transposes to [N][K] bf16 ------------------------
__global__ __launch_bounds__(256)
void transpose_w_kernel(const float* __restrict__ qw, const float* __restrict__ kw,
                        const float* __restrict__ vw, const float* __restrict__ ow,
                        const float* __restrict__ c1w,
                        unsigned short* __restrict__ qwT, unsigned short* __restrict__ kwT,
                        unsigned short* __restrict__ vwT, unsigned short* __restrict__ owT,
                        unsigned short* __restrict__ c1wT) {
  int id = blockIdx.x * 256 + threadIdx.x;
  // sizes: qw 65536 (K=256), kw 131072 (K=512), vw 131072, ow 65536, c1w 65536
  if (id < 65536) {
    int n = id >> 8, k = id & 255;
    qwT[id] = f2bf(qw[k * 256 + n]);
  } else if (id < 65536 + 131072) {
    int i = id - 65536; int n = i >> 9, k = i & 511;
    kwT[i] = f2bf(kw[k * 256 + n]);
  } else if (id < 65536 + 262144) {
    int i = id - (65536 + 131072); int n = i >> 9, k = i & 511;
    vwT[i] = f2bf(vw[k * 256 + n]);
  } else if (id < 131072 + 262144) {
    int i = id - (65536 + 262144); int n = i >> 8, k = i & 255;
    owT[i] = f2bf(ow[k * 256 + n]);
  } else if (id < 196608 + 262144) {
    int i = id - (131072 + 262144); int n = i >> 8, k = i & 255;
    c1wT[i] = f2bf(c1w[k * 256 + n]);
  }
}

// ------------- k1: edge-bias distance table (pre-scaled by log2(e)) ---------
__global__ __launch_bounds__(256)
void edge_table_kernel(const float* __restrict__ e1w, const float* __restrict__ e1b,
                       const float* __restrict__ e2w, const float* __restrict__ e2b,
                       float* __restrict__ tabG) {
  int i = blockIdx.x * 256 + threadIdx.x;
  if (i >= NTAB) return;
  float d = (i + 0.5f) * (10.0f / NTAB);
  float a0 = 0.f, a1 = 0.f, a2 = 0.f, a3 = 0.f;
  for (int j = 0; j < 256; ++j) {
    float v = fmaf(d, e1w[j], e1b[j]);
    float s = v / (1.0f + __expf(-v));       // silu
    float4 w2 = ((const float4*)e2w)[j];     // e2w is [256][4]
    a0 = fmaf(s, w2.x, a0);
    a1 = fmaf(s, w2.y, a1);
    a2 = fmaf(s, w2.z, a2);
    a3 = fmaf(s, w2.w, a3);
  }
  tabG[0 * NTAB + i] = (a0 + e2b[0]) * LOG2E;
  tabG[1 * NTAB + i] = (a1 + e2b[1]) * LOG2E;
  tabG[2 * NTAB + i] = (a2 + e2b[2]) * LOG2E;
  tabG[3 * NTAB + i] = (a3 + e2b[3]) * LOG2E;
}

// ------------- k2: one-wave 32x32 MFMA GEMM, A[M][K]·BT[N][K]^T + bias ------
// MODE 0: bf16 out row-major   MODE 1: bf16 out transposed [N][M]
// MODE 2: f32 out + residual   MODE 3: bf16 out, silu epilogue
template <int MODE>
__global__ __launch_bounds__(64)
void gemm32_kernel(const unsigned short* __restrict__ A, const unsigned short* __restrict__ BT,
                   const float* __restrict__ bias, void* __restrict__ out,
                   const float* __restrict__ resid, int M, int N, int K) {
  int lane = threadIdx.x;
  int lo = lane & 31, hi = lane >> 5;
  int m0 = blockIdx.x * 32, n0 = blockIdx.y * 32;
  const unsigned short* ap = A + (m0 + lo) * K + hi * 8;
  const unsigned short* bp = BT + (n0 + lo) * K + hi * 8;
  f32x16 acc;
#pragma unroll
  for (int i = 0; i < 16; ++i) acc[i] = 0.f;
  int nk = K / 16;
#pragma unroll 4
  for (int kk = 0; kk < nk; ++kk) {
    short8 a = load_bf8(ap + kk * 16);
    short8 b = load_bf8(bp + kk * 16);
    acc = mfma32(a, b, acc);
  }
  int n = n0 + lo;
  float bn = bias[n];
#pragma unroll
  for (int g = 0; g < 4; ++g) {
#pragma unroll
    for (int rr = 0; rr < 4; ++rr) {
      int r = g * 4 + rr;
      int m = m0 + g * 8 + hi * 4 + rr;     // C/D row = (r&3)+8*(r>>2)+4*hi
      float v = acc[r] + bn;
      if (MODE == 0) {
        ((unsigned short*)out)[m * N + n] = f2bf(v);
      } else if (MODE == 1) {
        ((unsigned short*)out)[n * M + m] = f2bf(v);
      } else if (MODE == 2) {
        ((float*)out)[m * N + n] = v + resid[m * N + n];
      } else {
        float sg = v / (1.0f + exp2h(-LOG2E * v)); // silu
        ((unsigned short*)out)[m * N + n] = f2bf(sg);
      }
    }
  }
}

// ------------- k3: flash cross-attention with geometry ----------------------
// grid: 32 q-tiles * NSPLIT j-splits; block: 4 waves = 4 heads.
__global__ __launch_bounds__(256)
void attn_kernel(const unsigned short* __restrict__ Qbf, const unsigned short* __restrict__ Kbf,
                 const unsigned short* __restrict__ VTbf,
                 const float* __restrict__ x_lig, const float* __restrict__ x_pocket,
                 const float* __restrict__ tabG,
                 float* __restrict__ partO, float4* __restrict__ partZC) {
  __shared__ float4 xch[CHUNK];            // x,y,z,0 per pocket atom of this chunk
  __shared__ float tab[NHEAD][NTAB];       // per-head bias table (log2-domain)

  int tid = threadIdx.x;
  int h = tid >> 6;
  int lane = tid & 63;
  int lo = lane & 31, hi = lane >> 5;
  int qt = blockIdx.x & 31;
  int split = blockIdx.x >> 5;
  int q0 = qt * 32;
  int j0g = split * CHUNK;

  for (int i = tid; i < CHUNK; i += 256) {
    float x = x_pocket[(j0g + i) * 3 + 0];
    float y = x_pocket[(j0g + i) * 3 + 1];
    float z = x_pocket[(j0g + i) * 3 + 2];
    float4 v; v.x = x; v.y = y; v.z = z; v.w = 0.f;
    xch[i] = v;
  }
  for (int i = tid; i < NHEAD * NTAB; i += 256) ((float*)tab)[i] = tabG[i];
  __syncthreads();

  int q = q0 + lo;
  float xl0 = x_lig[q * 3 + 0];
  float xl1 = x_lig[q * 3 + 1];
  float xl2 = x_lig[q * 3 + 2];

  short8 qfr[4];
#pragma unroll
  for (int kk = 0; kk < 4; ++kk)
    qfr[kk] = load_bf8(Qbf + q * HIDDEN + h * HDIM + kk * 16 + hi * 8);

  f32x16 O0, O1;
#pragma unroll
  for (int i = 0; i < 16; ++i) { O0[i] = 0.f; O1[i] = 0.f; }
  float Z = 0.f, c0 = 0.f, c1 = 0.f, c2 = 0.f;

#pragma unroll 1
  for (int t = 0; t < CHUNK / 32; ++t) {
    int jb = t * 32;
    // S^T[j,q] = K-tile · Q^T  (A rows = j, B cols = q)
    f32x16 s;
#pragma unroll
    for (int i = 0; i < 16; ++i) s[i] = 0.f;
#pragma unroll
    for (int kk = 0; kk < 4; ++kk) {
      short8 a = load_bf8(Kbf + (j0g + jb + lo) * HIDDEN + h * HDIM + kk * 16 + hi * 8);
      s = mfma32(a, qfr[kk], s);
    }
    // per-element: geometry + bias + exp2 (no running max needed; scores bounded)
    unsigned wp[8];
    float pprev = 0.f;
#pragma unroll
    for (int r = 0; r < 16; ++r) {
      int jl = (r & 3) + 8 * (r >> 2) + 4 * hi;  // C/D row of reg r
      float4 xp = xch[jb + jl];
      float dx = xp.x - xl0, dy = xp.y - xl1, dz = xp.z - xl2;
      float r2 = fmaf(dx, dx, fmaf(dy, dy, dz * dz));
      float r2c = fmaxf(r2, 1e-24f);
      float rinv = rsqh(r2c);
      float d = r2c * rinv;
      int idx = (int)(d * (NTAB / 10.0f));
      idx = idx > (NTAB - 1) ? (NTAB - 1) : idx;
      float b = tab[h][idx];
      float s2 = fmaf(s[r], QK_SCALE, b);
      float pe = (r2 < 100.0f) ? exp2h(s2) : 0.0f;  // mask d>=10 exactly
      Z += pe;
      float pr = pe * rinv;
      c0 = fmaf(pr, dx, c0);
      c1 = fmaf(pr, dy, c1);
      c2 = fmaf(pr, dz, c2);
      if (r & 1) wp[r >> 1] = pack2(pprev, pe); else pprev = pe;
    }
    // P^T -> B fragments (two 16-j subtiles) and PV MFMAs
#pragma unroll
    for (int sub = 0; sub < 2; ++sub) {
      unsigned W0 = wp[sub * 4 + 0], W1 = wp[sub * 4 + 1];
      unsigned W2 = wp[sub * 4 + 2], W3 = wp[sub * 4 + 3];
      unsigned e01 = (unsigned)__shfl_xor((int)(hi ? W0 : W2), 32);
      unsigned e23 = (unsigned)__shfl_xor((int)(hi ? W1 : W3), 32);
      U4S8 pb;
      pb.u.x = hi ? e01 : W0;
      pb.u.y = hi ? e23 : W1;
      pb.u.z = hi ? W2 : e01;
      pb.u.w = hi ? W3 : e23;
      const unsigned short* vbase =
          VTbf + (h * HDIM + lo) * NPOCK + j0g + jb + sub * 16 + hi * 8;
      short8 v0 = load_bf8(vbase);
      short8 v1 = load_bf8(vbase + 32 * NPOCK);
      O0 = mfma32(v0, pb.s, O0);
      O1 = mfma32(v1, pb.s, O1);
    }
  }

  // store flash partials: O^T rows d = (r&3)+8*(r>>2)+4*hi, col q = lo
  float* po = partO + (((q * NHEAD) + h) * NSPLIT + split) * HDIM;
#pragma unroll
  for (int g = 0; g < 4; ++g) {
    float4 s0; s0.x = O0[g * 4 + 0]; s0.y = O0[g * 4 + 1]; s0.z = O0[g * 4 + 2]; s0.w = O0[g * 4 + 3];
    *(float4*)(po + g * 8 + hi * 4) = s0;
    float4 s1; s1.x = O1[g * 4 + 0]; s1.y = O1[g * 4 + 1]; s1.z = O1[g * 4 + 2]; s1.w = O1[g * 4 + 3];
    *(float4*)(po + 32 + g * 8 + hi * 4) = s1;
  }
  float Zt = Z + __shfl_xor(Z, 32);
  float c0t = c0 + __shfl_xor(c0, 32);
  float c1t = c1 + __shfl_xor(c1, 32);
  float c2t = c2 + __shfl_xor(c2, 32);
  if (hi == 0) {
    float4 zc; zc.x = Zt; zc.y = c0t; zc.z = c1t; zc.w = c2t;
    partZC[((q * NHEAD) + h) * NSPLIT + split] = zc;
  }
}

// ------------- k4: combine splits -> h_attended (bf16) + coord messages -----
__global__ __launch_bounds__(256)
void combine_kernel(const float* __restrict__ partO, const float4* __restrict__ partZC,
                    unsigned short* __restrict__ hattb, float* __restrict__ cmsg) {
  int q = blockIdx.x;
  int t = threadIdx.x;
  int h = t >> 6, dl = t & 63;
  float Zh = 0.f;
#pragma unroll
  for (int s = 0; s < NSPLIT; ++s) Zh += partZC[(q * NHEAD + h) * NSPLIT + s].x;
  float o = 0.f;
#pragma unroll
  for (int s = 0; s < NSPLIT; ++s) o += partO[((q * NHEAD + h) * NSPLIT + s) * HDIM + dl];
  float inv = (Zh > 0.f) ? 1.0f / Zh : 0.f;  // fully-masked row -> 0 (nan_to_num)
  hattb[q * HIDDEN + h * HDIM + dl] = f2bf(o * inv);

  __shared__ float sm[NHEAD][3];
  if (t < NHEAD) {
    float zz = 0.f, a0 = 0.f, a1 = 0.f, a2 = 0.f;
    for (int s = 0; s < NSPLIT; ++s) {
      float4 v = partZC[(q * NHEAD + t) * NSPLIT + s];
      zz += v.x; a0 += v.y; a1 += v.z; a2 += v.w;
    }
    float iv = (zz > 0.f) ? 0.25f / zz : 0.f;   // mean over heads folded in
    sm[t][0] = a0 * iv; sm[t][1] = a1 * iv; sm[t][2] = a2 * iv;
  }
  __syncthreads();
  if (t < 3) cmsg[q * 3 + t] = sm[0][t] + sm[1][t] + sm[2][t] + sm[3][t];
}

// ------------- k6: coord scale dot + x_out ----------------------------------
__global__ __launch_bounds__(64)
void coord_kernel(const unsigned short* __restrict__ c1out, const float* __restrict__ c2w,
                  const float* __restrict__ c2b, const float* __restrict__ cmsg,
                  const float* __restrict__ x_lig, float* __restrict__ x_out) {
  int q = blockIdx.x;
  int lane = threadIdx.x;
  const unsigned short* row = c1out + q * HIDDEN + lane * 4;
  ushort4 tv = *(const ushort4*)row;
  float4 wv = *(const float4*)(c2w + lane * 4);
  float acc = bf2f(tv.x) * wv.x + bf2f(tv.y) * wv.y + bf2f(tv.z) * wv.z + bf2f(tv.w) * wv.w;
#pragma unroll
  for (int m = 32; m >= 1; m >>= 1) acc += __shfl_xor(acc, m);
  if (lane == 0) {
    float sc = acc + c2b[0];
    x_out[q * 3 + 0] = x_lig[q * 3 + 0] + sc * cmsg[q * 3 + 0];
    x_out[q * 3 + 1] = x_lig[q * 3 + 1] + sc * cmsg[q * 3 + 1];
    x_out[q * 3 + 2] = x_lig[q * 3 + 2] + sc * cmsg[q * 3 + 2];
  }
}

extern "C" void kernel_launch(void* const* d_in, const int* in_sizes, int n_in,
                              void* d_out, int out_size, void* d_ws, size_t ws_size,
                              hipStream_t stream) {
  const float* h_lig  = (const float*)d_in[0];
  const float* x_lig  = (const float*)d_in[1];
  const float* h_atom = (const float*)d_in[2];
  const float* x_pock = (const float*)d_in[3];
  const float* qw  = (const float*)d_in[4];
  const float* qb  = (const float*)d_in[5];
  const float* kw  = (const float*)d_in[6];
  const float* kb  = (const float*)d_in[7];
  const float* vw  = (const float*)d_in[8];
  const float* vb  = (const float*)d_in[9];
  const float* ow  = (const float*)d_in[10];
  const float* ob  = (const float*)d_in[11];
  const float* e1w = (const float*)d_in[12];
  const float* e1b = (const float*)d_in[13];
  const float* e2w = (const float*)d_in[14];
  const float* e2b = (const float*)d_in[15];
  const float* c1w = (const float*)d_in[16];
  const float* c1b = (const float*)d_in[17];
  const float* c2w = (const float*)d_in[18];
  const float* c2b = (const float*)d_in[19];

  char* w = (char*)d_ws;
  unsigned short* hAb  = (unsigned short*)w; w += (size_t)NPOCK * ADIM * 2;     // 8 MB
  unsigned short* hlb  = (unsigned short*)w; w += (size_t)NLIG * HIDDEN * 2;    // 0.5 MB
  unsigned short* qwT  = (unsigned short*)w; w += 256 * 256 * 2;
  unsigned short* kwT  = (unsigned short*)w; w += 256 * 512 * 2;
  unsigned short* vwT  = (unsigned short*)w; w += 256 * 512 * 2;
  unsigned short* owT  = (unsigned short*)w; w += 256 * 256 * 2;
  unsigned short* c1wT = (unsigned short*)w; w += 256 * 256 * 2;
  unsigned short* Qb   = (unsigned short*)w; w += (size_t)NLIG * HIDDEN * 2;
  unsigned short* Kb   = (unsigned short*)w; w += (size_t)NPOCK * HIDDEN * 2;   // 4 MB
  unsigned short* VTb  = (unsigned short*)w; w += (size_t)HIDDEN * NPOCK * 2;   // 4 MB
  float* tabG          = (float*)w;          w += NHEAD * NTAB * 4;
  float* partO         = (float*)w;          w += (size_t)NLIG * NHEAD * NSPLIT * HDIM * 4; // 16.8 MB
  float* partZC        = (float*)w;          w += (size_t)NLIG * NHEAD * NSPLIT * 4 * 4;    // 1 MB
  unsigned short* hatt = (unsigned short*)w; w += (size_t)NLIG * HIDDEN * 2;
  unsigned short* c1o  = (unsigned short*)w; w += (size_t)NLIG * HIDDEN * 2;
  float* cmsg          = (float*)w;          w += (size_t)NLIG * 3 * 4;

  float* hout = (float*)d_out;
  float* xout = ((float*)d_out) + (size_t)NLIG * HIDDEN;

  // k0: casts + weight transposes (independent)
  {
    int tot4 = (NPOCK * ADIM + NLIG * HIDDEN) / 4;
    cast_bf16_kernel<<<(tot4 + 255) / 256, 256, 0, stream>>>(h_atom, h_lig, hAb, hlb);
    transpose_w_kernel<<<(458752 + 255) / 256, 256, 0, stream>>>(qw, kw, vw, ow, c1w,
                                                                 qwT, kwT, vwT, owT, c1wT);
    edge_table_kernel<<<NTAB / 256, 256, 0, stream>>>(e1w, e1b, e2w, e2b, tabG);
  }
  // k2: projections
  gemm32_kernel<0><<<dim3(NLIG / 32, HIDDEN / 32), 64, 0, stream>>>(
      hlb, qwT, qb, (void*)Qb, nullptr, NLIG, HIDDEN, HIDDEN);
  gemm32_kernel<0><<<dim3(NPOCK / 32, HIDDEN / 32), 64, 0, stream>>>(
      hAb, kwT, kb, (void*)Kb, nullptr, NPOCK, HIDDEN, ADIM);
  gemm32_kernel<1><<<dim3(NPOCK / 32, HIDDEN / 32), 64, 0, stream>>>(
      hAb, vwT, vb, (void*)VTb, nullptr, NPOCK, HIDDEN, ADIM);
  // k3: attention
  attn_kernel<<<32 * NSPLIT, 256, 0, stream>>>(Qb, Kb, VTb, x_lig, x_pock, tabG,
                                               partO, (float4*)partZC);
  // k4: combine
  combine_kernel<<<NLIG, 256, 0, stream>>>(partO, (const float4*)partZC, hatt, cmsg);
  // epilogue GEMMs
  gemm32_kernel<2><<<dim3(NLIG / 32, HIDDEN / 32), 64, 0, stream>>>(
      hatt, owT, ob, (void*)hout, h_lig, NLIG, HIDDEN, HIDDEN);
  gemm32_kernel<3><<<dim3(NLIG / 32, HIDDEN / 32), 64, 0, stream>>>(
      hatt, c1wT, c1b, (void*)c1o, nullptr, NLIG, HIDDEN, HIDDEN);
  // k6: coordinate update
  coord_kernel<<<NLIG, 64, 0, stream>>>(c1o, c2w, c2b, cmsg, x_lig, xout);
}